// Round 8
// baseline (89.343 us; speedup 1.0000x reference)
//
#include <hip/hip_runtime.h>
#include <math.h>

#define B 8
#define N 2048
#define DIM 32
#define HID 64
#define KLIFT 16
#define DMODEL 256
#define KPROXY 16
#define KSEL 8.0f

typedef float f32x4 __attribute__((ext_vector_type(4)));
typedef short bf16x8 __attribute__((ext_vector_type(8)));

__device__ inline unsigned short f2bf(float f) {
  unsigned u = __float_as_uint(f);
  unsigned r = (u + 0x7FFFu + ((u >> 16) & 1u)) >> 16;  // RNE
  return (unsigned short)r;
}
__device__ inline float bf2f(unsigned short s) {
  return __uint_as_float(((unsigned)s) << 16);
}
__device__ inline float clip_temp(float lt) {
  return fminf(fmaxf(expf(lt), 0.1f), 10.f);
}

// ---------------- K1: saliency MLP + sq + bf16 hi/lo split + budget1 partials + nnd2 init
// VERBATIM from round-4 passing build.
__global__ __launch_bounds__(256) void k_prep(
    const float* __restrict__ x, const float* __restrict__ W1,
    const float* __restrict__ b1, const float* __restrict__ W2,
    const float* __restrict__ b2, const float* __restrict__ logt,
    float* __restrict__ sal, float* __restrict__ sq,
    unsigned short* __restrict__ Xhi, unsigned short* __restrict__ Xlo,
    float* __restrict__ partials1, unsigned* __restrict__ nnd2) {
  __shared__ float sW1[DIM * HID];
  __shared__ float sW2[HID], sb1[HID];
  __shared__ float red[4];
  int t = threadIdx.x;
  int lane = t & 63, wid = t >> 6;
  {
    const float4* s4 = (const float4*)W1;
    float4* d4 = (float4*)sW1;
    for (int i = t; i < DIM * HID / 4; i += 256) d4[i] = s4[i];
    if (t < HID) { sW2[t] = W2[t]; sb1[t] = b1[t]; }
  }
  __syncthreads();
  int p = blockIdx.x * 256 + t;       // 0..16383
  nnd2[p] = 0x7F7F7F7Fu;              // huge positive float bits
  float xr[DIM];
  const float4* xp = (const float4*)(x + (size_t)p * DIM);
#pragma unroll
  for (int i = 0; i < DIM / 4; i++) {
    float4 v = xp[i];
    xr[4 * i + 0] = v.x; xr[4 * i + 1] = v.y; xr[4 * i + 2] = v.z; xr[4 * i + 3] = v.w;
  }
  float s = 0.f;
#pragma unroll
  for (int d = 0; d < DIM; d++) s = fmaf(xr[d], xr[d], s);
  sq[p] = s;
  float h[HID];
#pragma unroll
  for (int j = 0; j < HID; j++) h[j] = sb1[j];
  for (int d = 0; d < DIM; d++) {
    float xv = xr[d];
    const float4* wrow = (const float4*)(&sW1[d * HID]);
#pragma unroll
    for (int j4 = 0; j4 < HID / 4; j4++) {
      float4 w = wrow[j4];
      h[4 * j4 + 0] = fmaf(xv, w.x, h[4 * j4 + 0]);
      h[4 * j4 + 1] = fmaf(xv, w.y, h[4 * j4 + 1]);
      h[4 * j4 + 2] = fmaf(xv, w.z, h[4 * j4 + 2]);
      h[4 * j4 + 3] = fmaf(xv, w.w, h[4 * j4 + 3]);
    }
  }
  float acc = b2[0];
#pragma unroll
  for (int j = 0; j < HID; j++) acc = fmaf(fmaxf(h[j], 0.f), sW2[j], acc);
  sal[p] = acc;
  // budget1 partial
  float temp = clip_temp(logt[0]);
  float y0 = 1.f / (1.f + expf(-((acc - 0.5f) / temp)));
  float part = y0;
#pragma unroll
  for (int off = 32; off >= 1; off >>= 1) part += __shfl_xor(part, off);
  if (lane == 0) red[wid] = part;
  __syncthreads();
  if (t == 0) partials1[blockIdx.x] = red[0] + red[1] + red[2] + red[3];
  // fragment-order bf16 split
  int bb = p >> 11, n = p & (N - 1);
  int tile = n >> 4, c = n & 15;
  size_t tb = ((size_t)(bb * 128 + tile)) * 64;
#pragma unroll
  for (int g = 0; g < 4; g++) {
    bf16x8 hv, lv;
#pragma unroll
    for (int j = 0; j < 8; j++) {
      float v = xr[g * 8 + j];
      unsigned short hb = f2bf(v);
      hv[j] = (short)hb;
      lv[j] = (short)f2bf(v - bf2f(hb));
    }
    size_t off = (tb + (size_t)g * 16 + c) * 8;
    *(bf16x8*)(Xhi + off) = hv;
    *(bf16x8*)(Xlo + off) = lv;
  }
}

// ---------------- K2: NN squared distance via split-bf16 MFMA Gram ----------------
// VERBATIM from round-4 passing build.
__global__ __launch_bounds__(256) void k_nnd(
    const unsigned short* __restrict__ Xhi, const unsigned short* __restrict__ Xlo,
    const float* __restrict__ sq, unsigned* __restrict__ nnd2) {
  int bid = blockIdx.x;
  int bb = bid >> 7;
  int nch = (bid >> 3) & 15;
  int mo = bid & 7;
  int t = threadIdx.x;
  int w = t >> 6, lane = t & 63;
  int c = lane & 15, g = lane >> 4;
  __shared__ unsigned short ldsH[16 * 512];
  __shared__ unsigned short ldsL[16 * 512];
  __shared__ float ssq[256];
  {
    size_t base = ((size_t)(bb * 128 + mo * 16)) * 512;
    const float4* srcH = (const float4*)(Xhi + base);
    const float4* srcL = (const float4*)(Xlo + base);
    float4* dH = (float4*)ldsH;
    float4* dL = (float4*)ldsL;
    for (int i = t; i < 1024; i += 256) { dH[i] = srcH[i]; dL[i] = srcL[i]; }
    ssq[t] = sq[bb * N + mo * 256 + t];
  }
  int nt0 = nch * 8 + w * 2, nt1 = nt0 + 1;
  bf16x8 ah0 = *(const bf16x8*)(Xhi + (((size_t)(bb * 128 + nt0)) * 64 + lane) * 8);
  bf16x8 al0 = *(const bf16x8*)(Xlo + (((size_t)(bb * 128 + nt0)) * 64 + lane) * 8);
  bf16x8 ah1 = *(const bf16x8*)(Xhi + (((size_t)(bb * 128 + nt1)) * 64 + lane) * 8);
  bf16x8 al1 = *(const bf16x8*)(Xlo + (((size_t)(bb * 128 + nt1)) * 64 + lane) * 8);
  __syncthreads();
  float mn0[4] = {1e30f, 1e30f, 1e30f, 1e30f};
  float mn1[4] = {1e30f, 1e30f, 1e30f, 1e30f};
  for (int tt = 0; tt < 16; tt++) {
    bf16x8 bh = ((const bf16x8*)(ldsH + tt * 512))[lane];
    bf16x8 bl2 = ((const bf16x8*)(ldsL + tt * 512))[lane];
    f32x4 a0 = {0.f, 0.f, 0.f, 0.f};
    f32x4 a1 = {0.f, 0.f, 0.f, 0.f};
    a0 = __builtin_amdgcn_mfma_f32_16x16x32_bf16(ah0, bh, a0, 0, 0, 0);
    a1 = __builtin_amdgcn_mfma_f32_16x16x32_bf16(ah1, bh, a1, 0, 0, 0);
    a0 = __builtin_amdgcn_mfma_f32_16x16x32_bf16(ah0, bl2, a0, 0, 0, 0);
    a1 = __builtin_amdgcn_mfma_f32_16x16x32_bf16(ah1, bl2, a1, 0, 0, 0);
    a0 = __builtin_amdgcn_mfma_f32_16x16x32_bf16(al0, bh, a0, 0, 0, 0);
    a1 = __builtin_amdgcn_mfma_f32_16x16x32_bf16(al1, bh, a1, 0, 0, 0);
    float sm = ssq[tt * 16 + c];
    int mtg = mo * 16 + tt;
    bool d0 = (mtg == nt0), d1 = (mtg == nt1);
#pragma unroll
    for (int r = 0; r < 4; r++) {
      float v0 = fmaf(-2.f, a0[r], sm);
      float v1 = fmaf(-2.f, a1[r], sm);
      if (d0 && c == 4 * g + r) v0 = 1e30f;   // mask self-distance
      if (d1 && c == 4 * g + r) v1 = 1e30f;
      mn0[r] = fminf(mn0[r], v0);
      mn1[r] = fminf(mn1[r], v1);
    }
  }
#pragma unroll
  for (int off = 1; off <= 8; off <<= 1) {
#pragma unroll
    for (int r = 0; r < 4; r++) {
      mn0[r] = fminf(mn0[r], __shfl_xor(mn0[r], off));
      mn1[r] = fminf(mn1[r], __shfl_xor(mn1[r], off));
    }
  }
  if (c == 0) {
#pragma unroll
    for (int r = 0; r < 4; r++) {
      int n0 = nt0 * 16 + 4 * g + r;
      float v = fmaxf(sq[bb * N + n0] + mn0[r], 0.f);
      atomicMin(&nnd2[bb * N + n0], __float_as_uint(v));
      int n1 = nt1 * 16 + 4 * g + r;
      v = fmaxf(sq[bb * N + n1] + mn1[r], 0.f);
      atomicMin(&nnd2[bb * N + n1], __float_as_uint(v));
    }
  }
}

// ---------------- K3: selector phase B — cn and partial g per 256-pt chunk ----------------
// VERBATIM from round-4 passing build.
__global__ __launch_bounds__(256) void k_c1(
    const float* __restrict__ x, const float* __restrict__ sal,
    const float* __restrict__ sq, const unsigned* __restrict__ nnd2,
    const float* __restrict__ logt, const float* __restrict__ partials1,
    float* __restrict__ gpart) {
  int bid = blockIdx.x;
  int bb = bid >> 3, ch = bid & 7;
  int t = threadIdx.x, lane = t & 63, wid = t >> 6;
  __shared__ float xs[256][33];
  __shared__ float cs[256];
  __shared__ float gsh[8][32];
  __shared__ float red32[4], red33[4];
  int n = ch * 256 + t;
  size_t base = (size_t)bb * N + n;
  float temp = clip_temp(logt[0]);
  float b1v = 0.f;
  for (int j = 0; j < 8; j++) b1v += partials1[bb * 8 + j];
  float scale1 = fminf(KSEL / fmaxf(b1v, 1e-6f), 1.f);
  float sv = sal[base];
  float y0 = 1.f / (1.f + expf(-((sv - 0.5f) / temp)));
  float y1 = y0 * scale1;
  float dv = sqrtf(__uint_as_float(nnd2[base]));
  float nrm = sqrtf(sq[base] + 3.f * dv * dv + sv * sv) + 1e-8f;
  float cn = y1 / nrm;
  cs[t] = cn;
  {
    const float4* xsrc = (const float4*)(x + ((size_t)bb * N + ch * 256) * DIM);
    for (int j = t; j < 2048; j += 256) {
      float4 v = xsrc[j];
      int pt = j >> 3, c4 = (j & 7) * 4;
      xs[pt][c4 + 0] = v.x; xs[pt][c4 + 1] = v.y;
      xs[pt][c4 + 2] = v.z; xs[pt][c4 + 3] = v.w;
    }
  }
  float v32 = cn * dv, v33 = cn * sv;
#pragma unroll
  for (int off = 32; off >= 1; off >>= 1) {
    v32 += __shfl_xor(v32, off);
    v33 += __shfl_xor(v33, off);
  }
  if (lane == 0) { red32[wid] = v32; red33[wid] = v33; }
  __syncthreads();
  if (t == 0) {
    gpart[(size_t)(bb * 8 + ch) * 36 + 32] = red32[0] + red32[1] + red32[2] + red32[3];
    gpart[(size_t)(bb * 8 + ch) * 36 + 33] = red33[0] + red33[1] + red33[2] + red33[3];
  }
  int d = t & 31, pg = t >> 5;
  float acc = 0.f;
#pragma unroll
  for (int i = 0; i < 32; i++) acc = fmaf(cs[pg * 32 + i], xs[pg * 32 + i][d], acc);
  gsh[pg][d] = acc;
  __syncthreads();
  if (t < 32) {
    float s = 0.f;
#pragma unroll
    for (int pgi = 0; pgi < 8; pgi++) s += gsh[pgi][t];
    gpart[(size_t)(bb * 8 + ch) * 36 + t] = s;
  }
}

// ---------------- K4: y2 pass (1 point/thread) + budget2 partials ----------------
// VERBATIM from round-4 passing build (output buffer renamed y2buf).
__global__ __launch_bounds__(256) void k_c(
    const float* __restrict__ x, const float* __restrict__ sal,
    const float* __restrict__ sq, const unsigned* __restrict__ nnd2,
    const float* __restrict__ logt, const float* __restrict__ partials1,
    const float* __restrict__ gpart, float* __restrict__ partials2,
    float* __restrict__ y2buf) {
  int bid = blockIdx.x;
  int bb = bid >> 3, ch = bid & 7;
  int t = threadIdx.x, lane = t & 63, wid = t >> 6;
  __shared__ float gfin[34];
  __shared__ float s1sh;
  __shared__ float red[4];
  if (t < 34) {
    float s = 0.f;
    for (int j = 0; j < 8; j++) s += gpart[(size_t)(bb * 8 + j) * 36 + t];
    gfin[t] = s;
  }
  if (t == 40) {
    float s = 0.f;
    for (int j = 0; j < 8; j++) s += partials1[bb * 8 + j];
    s1sh = fminf(KSEL / fmaxf(s, 1e-6f), 1.f);
  }
  __syncthreads();
  float scale1 = s1sh;
  int n = ch * 256 + t;
  size_t base = (size_t)bb * N + n;
  float temp = clip_temp(logt[0]);
  float sv = sal[base];
  float y0 = 1.f / (1.f + expf(-((sv - 0.5f) / temp)));
  float y1 = y0 * scale1;
  float dv = sqrtf(__uint_as_float(nnd2[base]));
  float nrm = sqrtf(sq[base] + 3.f * dv * dv + sv * sv) + 1e-8f;
  const float4* p4 = (const float4*)(x + base * DIM);
  float ov = 0.f;
#pragma unroll
  for (int cc = 0; cc < 8; cc++) {
    float4 v = p4[cc];
    ov = fmaf(v.x, gfin[4 * cc + 0], ov);
    ov = fmaf(v.y, gfin[4 * cc + 1], ov);
    ov = fmaf(v.z, gfin[4 * cc + 2], ov);
    ov = fmaf(v.w, gfin[4 * cc + 3], ov);
  }
  ov += 3.f * dv * gfin[32] + sv * gfin[33];
  ov /= nrm;
  float y2 = y1 / (1.f + ov);
  y2buf[base] = y2;              // unscaled
  float part = y2;
#pragma unroll
  for (int off = 32; off >= 1; off >>= 1) part += __shfl_xor(part, off);
  if (lane == 0) red[wid] = part;
  __syncthreads();
  if (t == 0) partials2[bb * 8 + ch] = red[0] + red[1] + red[2] + red[3];
}

// ---------------- K5: scale2 + ystar write + rank-based top-16 ----------------
// grid = 64 (8 b x 8 chunks), 256 threads. No serial selection rounds.
__global__ __launch_bounds__(256) void k_post(
    const float* __restrict__ y2buf, const float* __restrict__ partials2,
    float* __restrict__ ystar, int* __restrict__ topidx) {
  int bid = blockIdx.x;
  int bb = bid >> 3, ch = bid & 7;
  int t = threadIdx.x;
  __shared__ float yv[N];
  __shared__ float s2sh;
  if (t == 0) {
    float s = 0.f;
    for (int j = 0; j < 8; j++) s += partials2[bb * 8 + j];   // R4 tree
    s2sh = fminf(KSEL / fmaxf(s, 1e-6f), 1.f);
  }
  __syncthreads();
  float scale2 = s2sh;
  // stage full batch scaled into LDS (vectorized)
  {
    const float4* src = (const float4*)(y2buf + (size_t)bb * N);
    float4* dst = (float4*)yv;
#pragma unroll
    for (int i = 0; i < 2; i++) {
      float4 v = src[t + 256 * i];
      v.x *= scale2; v.y *= scale2; v.z *= scale2; v.w *= scale2;
      dst[t + 256 * i] = v;
    }
  }
  __syncthreads();
  // write this block's chunk to global
  int n = ch * 256 + t;
  float vi = yv[n];
  ystar[(size_t)bb * N + n] = vi;
  // rank: count j with (yv[j] > vi) || (yv[j] == vi && j < n)
  int cnt = 0;
  const float4* yv4 = (const float4*)yv;
  for (int j4 = 0; j4 < N / 4; j4++) {
    float4 v = yv4[j4];
    int j = j4 * 4;
    cnt += (v.x > vi || (v.x == vi && (j + 0) < n));
    cnt += (v.y > vi || (v.y == vi && (j + 1) < n));
    cnt += (v.z > vi || (v.z == vi && (j + 2) < n));
    cnt += (v.w > vi || (v.w == vi && (j + 3) < n));
  }
  if (cnt < KPROXY) topidx[bb * KPROXY + cnt] = n;
}

// ---------------- K6: lifted (selected rows only) + token projection ----------------
// VERBATIM structure from round-2 passing k_tokens. grid = B*KPROXY, 256 threads.
__global__ __launch_bounds__(256) void k_tok(
    const float* __restrict__ x, const unsigned* __restrict__ nnd2,
    const int* __restrict__ topidx, const float* __restrict__ mu,
    const float* __restrict__ sigma, const float* __restrict__ Wl,
    const float* __restrict__ bl, const float* __restrict__ Wp,
    const float* __restrict__ bp, float* __restrict__ tok) {
  int bk = blockIdx.x;
  int b = bk >> 4, k = bk & 15;
  int t = threadIdx.x;
  __shared__ float z[36]; __shared__ float lift[KLIFT]; __shared__ int srow;
  if (t == 0) srow = topidx[b * KPROXY + k];
  __syncthreads();
  int n = srow;
  if (t < 36) {
    float dvv;
    if (t < DIM) dvv = x[((size_t)(b * N + n)) * DIM + t];
    else if (t < 35) dvv = sqrtf(__uint_as_float(nnd2[b * N + n]));
    else dvv = 0.f;   // std of single NN distance is exactly 0
    z[t] = (dvv - mu[t]) / sigma[t];
  }
  __syncthreads();
  if (t < KLIFT) {
    float a = bl[t];
#pragma unroll
    for (int d = 0; d < 36; d++) a = fmaf(z[d], Wl[d * KLIFT + t], a);
    lift[t] = tanhf(a);
  }
  __syncthreads();
  float a = bp[t];
#pragma unroll
  for (int j = 0; j < KLIFT; j++) a = fmaf(lift[j], Wp[j * DMODEL + t], a);
  tok[(size_t)(b * KPROXY + k) * DMODEL + t] = a;
}

extern "C" void kernel_launch(void* const* d_in, const int* in_sizes, int n_in,
                              void* d_out, int out_size, void* d_ws, size_t ws_size,
                              hipStream_t stream) {
  const float* x  = (const float*)d_in[0];
  const float* lt = (const float*)d_in[1];
  const float* W1 = (const float*)d_in[2];
  const float* b1 = (const float*)d_in[3];
  const float* W2 = (const float*)d_in[4];
  const float* b2 = (const float*)d_in[5];
  const float* mu = (const float*)d_in[6];
  const float* sg = (const float*)d_in[7];
  const float* Wl = (const float*)d_in[8];
  const float* bl = (const float*)d_in[9];
  const float* Wp = (const float*)d_in[10];
  const float* bp = (const float*)d_in[11];

  float* tok = (float*)d_out;
  float* ystar = tok + B * KPROXY * DMODEL;

  char* ws = (char*)d_ws;
  float* sal          = (float*)(ws);                    // 64 KB
  float* sq           = (float*)(ws + 65536);            // 64 KB
  unsigned* nnd2      = (unsigned*)(ws + 131072);        // 64 KB (float bits)
  float* y2buf        = (float*)(ws + 196608);           // 64 KB (unscaled y2)
  float* partials1    = (float*)(ws + 262144);           // 64 f
  float* gpart        = (float*)(ws + 262656);           // 8*8*36 f
  float* partials2    = (float*)(ws + 272384);           // 64 f
  int* topidx         = (int*)(ws + 272896);             // 128 i32
  unsigned short* Xhi = (unsigned short*)(ws + 327680);  // 1 MB
  unsigned short* Xlo = (unsigned short*)(ws + 327680 + 1048576); // 1 MB

  k_prep<<<B * N / 256, 256, 0, stream>>>(x, W1, b1, W2, b2, lt, sal, sq, Xhi, Xlo, partials1, nnd2);
  k_nnd<<<B * 16 * 8, 256, 0, stream>>>(Xhi, Xlo, sq, nnd2);
  k_c1<<<B * 8, 256, 0, stream>>>(x, sal, sq, nnd2, lt, partials1, gpart);
  k_c<<<B * 8, 256, 0, stream>>>(x, sal, sq, nnd2, lt, partials1, gpart, partials2, y2buf);
  k_post<<<B * 8, 256, 0, stream>>>(y2buf, partials2, ystar, topidx);
  k_tok<<<B * KPROXY, 256, 0, stream>>>(x, nnd2, topidx, mu, sg, Wl, bl, Wp, bp, tok);
}

// Round 9
// 57.661 us; speedup vs baseline: 1.5495x; 1.5495x over previous
//
#include <hip/hip_runtime.h>
#include <math.h>

#define B 8
#define N 2048
#define DIM 32
#define HID 64
#define KLIFT 16
#define DMODEL 256
#define KPROXY 16
#define KSEL 8.0f

typedef float f32x4 __attribute__((ext_vector_type(4)));
typedef short bf16x8 __attribute__((ext_vector_type(8)));

__device__ inline unsigned short f2bf(float f) {
  unsigned u = __float_as_uint(f);
  unsigned r = (u + 0x7FFFu + ((u >> 16) & 1u)) >> 16;  // RNE
  return (unsigned short)r;
}
__device__ inline float bf2f(unsigned short s) {
  return __uint_as_float(((unsigned)s) << 16);
}
__device__ inline float clip_temp(float lt) {
  return fminf(fmaxf(expf(lt), 0.1f), 10.f);
}

// ---------------- K1: saliency MLP + sq + bf16 hi/lo split + budget1 partials + nnd2 init
// VERBATIM from round-4/8 passing builds.
__global__ __launch_bounds__(256) void k_prep(
    const float* __restrict__ x, const float* __restrict__ W1,
    const float* __restrict__ b1, const float* __restrict__ W2,
    const float* __restrict__ b2, const float* __restrict__ logt,
    float* __restrict__ sal, float* __restrict__ sq,
    unsigned short* __restrict__ Xhi, unsigned short* __restrict__ Xlo,
    float* __restrict__ partials1, unsigned* __restrict__ nnd2) {
  __shared__ float sW1[DIM * HID];
  __shared__ float sW2[HID], sb1[HID];
  __shared__ float red[4];
  int t = threadIdx.x;
  int lane = t & 63, wid = t >> 6;
  {
    const float4* s4 = (const float4*)W1;
    float4* d4 = (float4*)sW1;
    for (int i = t; i < DIM * HID / 4; i += 256) d4[i] = s4[i];
    if (t < HID) { sW2[t] = W2[t]; sb1[t] = b1[t]; }
  }
  __syncthreads();
  int p = blockIdx.x * 256 + t;       // 0..16383
  nnd2[p] = 0x7F7F7F7Fu;              // huge positive float bits
  float xr[DIM];
  const float4* xp = (const float4*)(x + (size_t)p * DIM);
#pragma unroll
  for (int i = 0; i < DIM / 4; i++) {
    float4 v = xp[i];
    xr[4 * i + 0] = v.x; xr[4 * i + 1] = v.y; xr[4 * i + 2] = v.z; xr[4 * i + 3] = v.w;
  }
  float s = 0.f;
#pragma unroll
  for (int d = 0; d < DIM; d++) s = fmaf(xr[d], xr[d], s);
  sq[p] = s;
  float h[HID];
#pragma unroll
  for (int j = 0; j < HID; j++) h[j] = sb1[j];
  for (int d = 0; d < DIM; d++) {
    float xv = xr[d];
    const float4* wrow = (const float4*)(&sW1[d * HID]);
#pragma unroll
    for (int j4 = 0; j4 < HID / 4; j4++) {
      float4 w = wrow[j4];
      h[4 * j4 + 0] = fmaf(xv, w.x, h[4 * j4 + 0]);
      h[4 * j4 + 1] = fmaf(xv, w.y, h[4 * j4 + 1]);
      h[4 * j4 + 2] = fmaf(xv, w.z, h[4 * j4 + 2]);
      h[4 * j4 + 3] = fmaf(xv, w.w, h[4 * j4 + 3]);
    }
  }
  float acc = b2[0];
#pragma unroll
  for (int j = 0; j < HID; j++) acc = fmaf(fmaxf(h[j], 0.f), sW2[j], acc);
  sal[p] = acc;
  float temp = clip_temp(logt[0]);
  float y0 = 1.f / (1.f + expf(-((acc - 0.5f) / temp)));
  float part = y0;
#pragma unroll
  for (int off = 32; off >= 1; off >>= 1) part += __shfl_xor(part, off);
  if (lane == 0) red[wid] = part;
  __syncthreads();
  if (t == 0) partials1[blockIdx.x] = red[0] + red[1] + red[2] + red[3];
  int bb = p >> 11, n = p & (N - 1);
  int tile = n >> 4, c = n & 15;
  size_t tb = ((size_t)(bb * 128 + tile)) * 64;
#pragma unroll
  for (int g = 0; g < 4; g++) {
    bf16x8 hv, lv;
#pragma unroll
    for (int j = 0; j < 8; j++) {
      float v = xr[g * 8 + j];
      unsigned short hb = f2bf(v);
      hv[j] = (short)hb;
      lv[j] = (short)f2bf(v - bf2f(hb));
    }
    size_t off = (tb + (size_t)g * 16 + c) * 8;
    *(bf16x8*)(Xhi + off) = hv;
    *(bf16x8*)(Xlo + off) = lv;
  }
}

// ---------------- K2: NN squared distance via split-bf16 MFMA Gram ----------------
// VERBATIM from round-4/8 passing builds.
__global__ __launch_bounds__(256) void k_nnd(
    const unsigned short* __restrict__ Xhi, const unsigned short* __restrict__ Xlo,
    const float* __restrict__ sq, unsigned* __restrict__ nnd2) {
  int bid = blockIdx.x;
  int bb = bid >> 7;
  int nch = (bid >> 3) & 15;
  int mo = bid & 7;
  int t = threadIdx.x;
  int w = t >> 6, lane = t & 63;
  int c = lane & 15, g = lane >> 4;
  __shared__ unsigned short ldsH[16 * 512];
  __shared__ unsigned short ldsL[16 * 512];
  __shared__ float ssq[256];
  {
    size_t base = ((size_t)(bb * 128 + mo * 16)) * 512;
    const float4* srcH = (const float4*)(Xhi + base);
    const float4* srcL = (const float4*)(Xlo + base);
    float4* dH = (float4*)ldsH;
    float4* dL = (float4*)ldsL;
    for (int i = t; i < 1024; i += 256) { dH[i] = srcH[i]; dL[i] = srcL[i]; }
    ssq[t] = sq[bb * N + mo * 256 + t];
  }
  int nt0 = nch * 8 + w * 2, nt1 = nt0 + 1;
  bf16x8 ah0 = *(const bf16x8*)(Xhi + (((size_t)(bb * 128 + nt0)) * 64 + lane) * 8);
  bf16x8 al0 = *(const bf16x8*)(Xlo + (((size_t)(bb * 128 + nt0)) * 64 + lane) * 8);
  bf16x8 ah1 = *(const bf16x8*)(Xhi + (((size_t)(bb * 128 + nt1)) * 64 + lane) * 8);
  bf16x8 al1 = *(const bf16x8*)(Xlo + (((size_t)(bb * 128 + nt1)) * 64 + lane) * 8);
  __syncthreads();
  float mn0[4] = {1e30f, 1e30f, 1e30f, 1e30f};
  float mn1[4] = {1e30f, 1e30f, 1e30f, 1e30f};
  for (int tt = 0; tt < 16; tt++) {
    bf16x8 bh = ((const bf16x8*)(ldsH + tt * 512))[lane];
    bf16x8 bl2 = ((const bf16x8*)(ldsL + tt * 512))[lane];
    f32x4 a0 = {0.f, 0.f, 0.f, 0.f};
    f32x4 a1 = {0.f, 0.f, 0.f, 0.f};
    a0 = __builtin_amdgcn_mfma_f32_16x16x32_bf16(ah0, bh, a0, 0, 0, 0);
    a1 = __builtin_amdgcn_mfma_f32_16x16x32_bf16(ah1, bh, a1, 0, 0, 0);
    a0 = __builtin_amdgcn_mfma_f32_16x16x32_bf16(ah0, bl2, a0, 0, 0, 0);
    a1 = __builtin_amdgcn_mfma_f32_16x16x32_bf16(ah1, bl2, a1, 0, 0, 0);
    a0 = __builtin_amdgcn_mfma_f32_16x16x32_bf16(al0, bh, a0, 0, 0, 0);
    a1 = __builtin_amdgcn_mfma_f32_16x16x32_bf16(al1, bh, a1, 0, 0, 0);
    float sm = ssq[tt * 16 + c];
    int mtg = mo * 16 + tt;
    bool d0 = (mtg == nt0), d1 = (mtg == nt1);
#pragma unroll
    for (int r = 0; r < 4; r++) {
      float v0 = fmaf(-2.f, a0[r], sm);
      float v1 = fmaf(-2.f, a1[r], sm);
      if (d0 && c == 4 * g + r) v0 = 1e30f;   // mask self-distance
      if (d1 && c == 4 * g + r) v1 = 1e30f;
      mn0[r] = fminf(mn0[r], v0);
      mn1[r] = fminf(mn1[r], v1);
    }
  }
#pragma unroll
  for (int off = 1; off <= 8; off <<= 1) {
#pragma unroll
    for (int r = 0; r < 4; r++) {
      mn0[r] = fminf(mn0[r], __shfl_xor(mn0[r], off));
      mn1[r] = fminf(mn1[r], __shfl_xor(mn1[r], off));
    }
  }
  if (c == 0) {
#pragma unroll
    for (int r = 0; r < 4; r++) {
      int n0 = nt0 * 16 + 4 * g + r;
      float v = fmaxf(sq[bb * N + n0] + mn0[r], 0.f);
      atomicMin(&nnd2[bb * N + n0], __float_as_uint(v));
      int n1 = nt1 * 16 + 4 * g + r;
      v = fmaxf(sq[bb * N + n1] + mn1[r], 0.f);
      atomicMin(&nnd2[bb * N + n1], __float_as_uint(v));
    }
  }
}

// ---------------- K3: selector phase B — VERBATIM from round-4/8 ----------------
__global__ __launch_bounds__(256) void k_c1(
    const float* __restrict__ x, const float* __restrict__ sal,
    const float* __restrict__ sq, const unsigned* __restrict__ nnd2,
    const float* __restrict__ logt, const float* __restrict__ partials1,
    float* __restrict__ gpart) {
  int bid = blockIdx.x;
  int bb = bid >> 3, ch = bid & 7;
  int t = threadIdx.x, lane = t & 63, wid = t >> 6;
  __shared__ float xs[256][33];
  __shared__ float cs[256];
  __shared__ float gsh[8][32];
  __shared__ float red32[4], red33[4];
  int n = ch * 256 + t;
  size_t base = (size_t)bb * N + n;
  float temp = clip_temp(logt[0]);
  float b1v = 0.f;
  for (int j = 0; j < 8; j++) b1v += partials1[bb * 8 + j];
  float scale1 = fminf(KSEL / fmaxf(b1v, 1e-6f), 1.f);
  float sv = sal[base];
  float y0 = 1.f / (1.f + expf(-((sv - 0.5f) / temp)));
  float y1 = y0 * scale1;
  float dv = sqrtf(__uint_as_float(nnd2[base]));
  float nrm = sqrtf(sq[base] + 3.f * dv * dv + sv * sv) + 1e-8f;
  float cn = y1 / nrm;
  cs[t] = cn;
  {
    const float4* xsrc = (const float4*)(x + ((size_t)bb * N + ch * 256) * DIM);
    for (int j = t; j < 2048; j += 256) {
      float4 v = xsrc[j];
      int pt = j >> 3, c4 = (j & 7) * 4;
      xs[pt][c4 + 0] = v.x; xs[pt][c4 + 1] = v.y;
      xs[pt][c4 + 2] = v.z; xs[pt][c4 + 3] = v.w;
    }
  }
  float v32 = cn * dv, v33 = cn * sv;
#pragma unroll
  for (int off = 32; off >= 1; off >>= 1) {
    v32 += __shfl_xor(v32, off);
    v33 += __shfl_xor(v33, off);
  }
  if (lane == 0) { red32[wid] = v32; red33[wid] = v33; }
  __syncthreads();
  if (t == 0) {
    gpart[(size_t)(bb * 8 + ch) * 36 + 32] = red32[0] + red32[1] + red32[2] + red32[3];
    gpart[(size_t)(bb * 8 + ch) * 36 + 33] = red33[0] + red33[1] + red33[2] + red33[3];
  }
  int d = t & 31, pg = t >> 5;
  float acc = 0.f;
#pragma unroll
  for (int i = 0; i < 32; i++) acc = fmaf(cs[pg * 32 + i], xs[pg * 32 + i][d], acc);
  gsh[pg][d] = acc;
  __syncthreads();
  if (t < 32) {
    float s = 0.f;
#pragma unroll
    for (int pgi = 0; pgi < 8; pgi++) s += gsh[pgi][t];
    gpart[(size_t)(bb * 8 + ch) * 36 + t] = s;
  }
}

// ---------------- K4: y2 pass + budget2 partials — VERBATIM from round-8 ----------------
__global__ __launch_bounds__(256) void k_c(
    const float* __restrict__ x, const float* __restrict__ sal,
    const float* __restrict__ sq, const unsigned* __restrict__ nnd2,
    const float* __restrict__ logt, const float* __restrict__ partials1,
    const float* __restrict__ gpart, float* __restrict__ partials2,
    float* __restrict__ y2buf) {
  int bid = blockIdx.x;
  int bb = bid >> 3, ch = bid & 7;
  int t = threadIdx.x, lane = t & 63, wid = t >> 6;
  __shared__ float gfin[34];
  __shared__ float s1sh;
  __shared__ float red[4];
  if (t < 34) {
    float s = 0.f;
    for (int j = 0; j < 8; j++) s += gpart[(size_t)(bb * 8 + j) * 36 + t];
    gfin[t] = s;
  }
  if (t == 40) {
    float s = 0.f;
    for (int j = 0; j < 8; j++) s += partials1[bb * 8 + j];
    s1sh = fminf(KSEL / fmaxf(s, 1e-6f), 1.f);
  }
  __syncthreads();
  float scale1 = s1sh;
  int n = ch * 256 + t;
  size_t base = (size_t)bb * N + n;
  float temp = clip_temp(logt[0]);
  float sv = sal[base];
  float y0 = 1.f / (1.f + expf(-((sv - 0.5f) / temp)));
  float y1 = y0 * scale1;
  float dv = sqrtf(__uint_as_float(nnd2[base]));
  float nrm = sqrtf(sq[base] + 3.f * dv * dv + sv * sv) + 1e-8f;
  const float4* p4 = (const float4*)(x + base * DIM);
  float ov = 0.f;
#pragma unroll
  for (int cc = 0; cc < 8; cc++) {
    float4 v = p4[cc];
    ov = fmaf(v.x, gfin[4 * cc + 0], ov);
    ov = fmaf(v.y, gfin[4 * cc + 1], ov);
    ov = fmaf(v.z, gfin[4 * cc + 2], ov);
    ov = fmaf(v.w, gfin[4 * cc + 3], ov);
  }
  ov += 3.f * dv * gfin[32] + sv * gfin[33];
  ov /= nrm;
  float y2 = y1 / (1.f + ov);
  y2buf[base] = y2;              // unscaled
  float part = y2;
#pragma unroll
  for (int off = 32; off >= 1; off >>= 1) part += __shfl_xor(part, off);
  if (lane == 0) red[wid] = part;
  __syncthreads();
  if (t == 0) partials2[bb * 8 + ch] = red[0] + red[1] + red[2] + red[3];
}

// ---------------- K5: scale2 + ystar + top-16 (LDS-only; R7-proven selection) ----------------
// 8 blocks x 1024 threads. Reads ONLY y2buf + partials2 (L2-hot, 8 KB/batch).
__global__ __launch_bounds__(1024) void k_post(
    const float* __restrict__ y2buf, const float* __restrict__ partials2,
    float* __restrict__ ystar, int* __restrict__ topidx) {
  int bb = blockIdx.x, t = threadIdx.x;
  int lane = t & 63, wid = t >> 6;   // 16 waves
  __shared__ float yv[N];
  __shared__ float s2sh;
  __shared__ float candv[256];
  __shared__ int candi[256];
  if (t == 0) {
    float s = 0.f;
    for (int j = 0; j < 8; j++) s += partials2[bb * 8 + j];   // R4 summation tree
    s2sh = fminf(KSEL / fmaxf(s, 1e-6f), 1.f);
  }
  __syncthreads();
  float scale2 = s2sh;
  size_t base = (size_t)bb * N;
  float ys0 = y2buf[base + t] * scale2;
  float ys1 = y2buf[base + t + 1024] * scale2;
  yv[t] = ys0; yv[t + 1024] = ys1;
  ystar[base + t] = ys0; ystar[base + t + 1024] = ys1;
  __syncthreads();
  // ---- stage 1 (R7-verbatim): wave w owns points [w*128, w*128+128) ----
  {
    float lv0 = yv[wid * 128 + lane];      int li0 = wid * 128 + lane;
    float lv1 = yv[wid * 128 + 64 + lane]; int li1 = li0 + 64;
    for (int r = 0; r < KPROXY; r++) {
      float bv = lv0; int bi = li0;
      if (lv1 > bv) { bv = lv1; bi = li1; }   // li1 > li0: tie keeps lower
#pragma unroll
      for (int off = 1; off < 64; off <<= 1) {
        float ovv = __shfl_xor(bv, off);
        int oi = __shfl_xor(bi, off);
        if (ovv > bv || (ovv == bv && oi < bi)) { bv = ovv; bi = oi; }
      }
      if (lane == 0) { candv[wid * 16 + r] = bv; candi[wid * 16 + r] = bi; }
      if (li0 == bi) lv0 = -1e30f;
      if (li1 == bi) lv1 = -1e30f;
    }
  }
  __syncthreads();
  // ---- stage 2 (R7-verbatim): wave 0 merges 256 candidates ----
  if (wid == 0) {
    float cv0 = candv[lane], cv1 = candv[lane + 64];
    float cv2 = candv[lane + 128], cv3 = candv[lane + 192];
    int ci0 = candi[lane], ci1 = candi[lane + 64];
    int ci2 = candi[lane + 128], ci3 = candi[lane + 192];
    for (int r = 0; r < KPROXY; r++) {
      float bv = cv0; int bi = ci0;
      if (cv1 > bv) { bv = cv1; bi = ci1; }   // ci1 > ci0 always
      if (cv2 > bv) { bv = cv2; bi = ci2; }
      if (cv3 > bv) { bv = cv3; bi = ci3; }
#pragma unroll
      for (int off = 1; off < 64; off <<= 1) {
        float ovv = __shfl_xor(bv, off);
        int oi = __shfl_xor(bi, off);
        if (ovv > bv || (ovv == bv && oi < bi)) { bv = ovv; bi = oi; }
      }
      if (lane == 0) topidx[bb * KPROXY + r] = bi;
      if (ci0 == bi) cv0 = -1e30f;
      if (ci1 == bi) cv1 = -1e30f;
      if (ci2 == bi) cv2 = -1e30f;
      if (ci3 == bi) cv3 = -1e30f;
    }
  }
}

// ---------------- K6: tokens — VERBATIM from round-8 ----------------
__global__ __launch_bounds__(256) void k_tok(
    const float* __restrict__ x, const unsigned* __restrict__ nnd2,
    const int* __restrict__ topidx, const float* __restrict__ mu,
    const float* __restrict__ sigma, const float* __restrict__ Wl,
    const float* __restrict__ bl, const float* __restrict__ Wp,
    const float* __restrict__ bp, float* __restrict__ tok) {
  int bk = blockIdx.x;
  int b = bk >> 4, k = bk & 15;
  int t = threadIdx.x;
  __shared__ float z[36]; __shared__ float lift[KLIFT]; __shared__ int srow;
  if (t == 0) srow = topidx[b * KPROXY + k];
  __syncthreads();
  int n = srow;
  if (t < 36) {
    float dvv;
    if (t < DIM) dvv = x[((size_t)(b * N + n)) * DIM + t];
    else if (t < 35) dvv = sqrtf(__uint_as_float(nnd2[b * N + n]));
    else dvv = 0.f;   // std of single NN distance is exactly 0
    z[t] = (dvv - mu[t]) / sigma[t];
  }
  __syncthreads();
  if (t < KLIFT) {
    float a = bl[t];
#pragma unroll
    for (int d = 0; d < 36; d++) a = fmaf(z[d], Wl[d * KLIFT + t], a);
    lift[t] = tanhf(a);
  }
  __syncthreads();
  float a = bp[t];
#pragma unroll
  for (int j = 0; j < KLIFT; j++) a = fmaf(lift[j], Wp[j * DMODEL + t], a);
  tok[(size_t)(b * KPROXY + k) * DMODEL + t] = a;
}

extern "C" void kernel_launch(void* const* d_in, const int* in_sizes, int n_in,
                              void* d_out, int out_size, void* d_ws, size_t ws_size,
                              hipStream_t stream) {
  const float* x  = (const float*)d_in[0];
  const float* lt = (const float*)d_in[1];
  const float* W1 = (const float*)d_in[2];
  const float* b1 = (const float*)d_in[3];
  const float* W2 = (const float*)d_in[4];
  const float* b2 = (const float*)d_in[5];
  const float* mu = (const float*)d_in[6];
  const float* sg = (const float*)d_in[7];
  const float* Wl = (const float*)d_in[8];
  const float* bl = (const float*)d_in[9];
  const float* Wp = (const float*)d_in[10];
  const float* bp = (const float*)d_in[11];

  float* tok = (float*)d_out;
  float* ystar = tok + B * KPROXY * DMODEL;

  char* ws = (char*)d_ws;
  float* sal          = (float*)(ws);                    // 64 KB
  float* sq           = (float*)(ws + 65536);            // 64 KB
  unsigned* nnd2      = (unsigned*)(ws + 131072);        // 64 KB (float bits)
  float* y2buf        = (float*)(ws + 196608);           // 64 KB (unscaled y2)
  float* partials1    = (float*)(ws + 262144);           // 64 f
  float* gpart        = (float*)(ws + 262656);           // 8*8*36 f
  float* partials2    = (float*)(ws + 272384);           // 64 f
  int* topidx         = (int*)(ws + 272896);             // 128 i32
  unsigned short* Xhi = (unsigned short*)(ws + 327680);  // 1 MB
  unsigned short* Xlo = (unsigned short*)(ws + 327680 + 1048576); // 1 MB

  k_prep<<<B * N / 256, 256, 0, stream>>>(x, W1, b1, W2, b2, lt, sal, sq, Xhi, Xlo, partials1, nnd2);
  k_nnd<<<B * 16 * 8, 256, 0, stream>>>(Xhi, Xlo, sq, nnd2);
  k_c1<<<B * 8, 256, 0, stream>>>(x, sal, sq, nnd2, lt, partials1, gpart);
  k_c<<<B * 8, 256, 0, stream>>>(x, sal, sq, nnd2, lt, partials1, gpart, partials2, y2buf);
  k_post<<<B, 1024, 0, stream>>>(y2buf, partials2, ystar, topidx);
  k_tok<<<B * KPROXY, 256, 0, stream>>>(x, nnd2, topidx, mu, sg, Wl, bl, Wp, bp, tok);
}